// Round 13
// baseline (150.927 us; speedup 1.0000x reference)
//
#include <hip/hip_runtime.h>
#include <hip/hip_bf16.h>
#include <math.h>

#define NROWS 32768
#define DD    1024
#define EE    640
#define VV    320
#define BM    128
#define KT    32      // DD/32
#define CTN   40      // EE/16

typedef __attribute__((ext_vector_type(8))) short short8;
typedef __attribute__((ext_vector_type(4))) short short4v;
typedef __attribute__((ext_vector_type(4))) float float4v;

static __device__ __forceinline__ unsigned short f2bf(float f) {
    unsigned int u = __float_as_uint(f);
    return (unsigned short)((u + 0x7fffu + ((u >> 16) & 1u)) >> 16); // RNE
}

// Pack W [K=1024][N=640] fp32 -> bf16, MFMA fragment layout:
// frag(kt, ct): lane l, elem e  <=  W[kt*32 + (l>>4)*8 + e][ct*16 + (l&15)]
__global__ void pack_w(const float* __restrict__ W, unsigned short* __restrict__ bp)
{
    const int t = threadIdx.x;
    const int tile = blockIdx.x * 4 + (t >> 6);   // 0..1279 = kt*40+ct
    const int lane = t & 63;
    const int kt = tile / CTN, ct = tile % CTN;
    const int k0 = kt * 32 + (lane >> 4) * 8;
    const int col = ct * 16 + (lane & 15);
    unsigned short v1[8];
    #pragma unroll
    for (int e = 0; e < 8; ++e)
        v1[e] = f2bf(W[(size_t)(k0 + e) * EE + col]);
    *(short8*)(bp + ((size_t)tile * 64 + lane) * 8) = *(const short8*)v1;
}

// Fused (R2 structure, single split): 256 blocks x 512 threads.
// Block: 128 rows x all 640 cols. Wave w: rg=w>>2 (64-row half), cg=w&3
// (160 cols = 10 frags). acc[4][10]. B: per-wave global->reg streaming from
// L2-resident packed fragments (NO LDS, NO barrier on B path). A: 2x8KB LDS
// dbuf, one __syncthreads per kt guarding only the 16B/thread A-stage.
__global__ __launch_bounds__(512, 2) void fused_vq(
    const float* __restrict__ x, const unsigned short* __restrict__ bp,
    const float* __restrict__ bias, const float* __restrict__ cb,
    const float* __restrict__ gum, float* __restrict__ out,
    float* __restrict__ probs_rep)
{
    __shared__ unsigned short As[2][BM * 32];   // 2 x 8 KB
    __shared__ float probs_blk[EE];
    __shared__ float pmax[4][BM];
    __shared__ float psum[4][BM];
    __shared__ int   pidx[4][BM];
    __shared__ int   fidx[BM][2];
    __shared__ float finv[BM][2];

    const int t    = threadIdx.x;
    const int lane = t & 63;
    const int w    = t >> 6;
    const int rg   = w >> 2;            // 64-row half
    const int cg   = w & 3;             // 160-col group
    const int n0   = blockIdx.x * BM;

    float4v acc[4][10];
    #pragma unroll
    for (int rf = 0; rf < 4; ++rf)
        #pragma unroll
        for (int ct = 0; ct < 10; ++ct)
            acc[rf][ct] = (float4v)0.f;

    // A staging: thread t stages quads t (rows 0..63) and t+512 (rows 64..127)
    const int r0 = t >> 3, kq0 = t & 7;
    const int abase0 = (r0 >> 4)*512 + ((r0 & 15) + ((kq0 >> 1) << 4))*8 + ((kq0 & 1) << 2);
    const int abase1 = abase0 + 4*512;            // rows +64 -> rowfrag +4
    const float* xr0 = x + (size_t)(n0 + r0) * DD + kq0 * 4;
    const float* xr1 = xr0 + (size_t)64 * DD;

    auto writeA = [&](int bb, int base, float4 v) {
        short4v s;
        s[0] = (short)f2bf(v.x); s[1] = (short)f2bf(v.y);
        s[2] = (short)f2bf(v.z); s[3] = (short)f2bf(v.w);
        *(short4v*)&As[bb][base] = s;
    };

    // prologue
    writeA(0, abase0, *(const float4*)(xr0));
    writeA(0, abase1, *(const float4*)(xr1));
    __syncthreads();

    for (int kt = 0; kt < KT; ++kt) {
        const int bb = kt & 1;
        const bool more = (kt + 1 < KT);
        float4 p0, p1;
        if (more) {                                // issue-early
            p0 = *(const float4*)(xr0 + (kt + 1) * 32);
            p1 = *(const float4*)(xr1 + (kt + 1) * 32);
        }
        short8 af[4];
        #pragma unroll
        for (int rf = 0; rf < 4; ++rf)
            af[rf] = *(const short8*)&As[bb][(rg*4 + rf)*512 + lane*8];

        const unsigned short* fb = bp + (((size_t)kt*CTN + cg*10)*64 + lane)*8;
        #pragma unroll
        for (int ct = 0; ct < 10; ++ct) {
            short8 bf = *(const short8*)(fb + ct*512);
            #pragma unroll
            for (int rf = 0; rf < 4; ++rf)
                acc[rf][ct] = __builtin_amdgcn_mfma_f32_16x16x32_bf16(af[rf], bf, acc[rf][ct], 0, 0, 0);
        }
        if (more) {                                // write-late
            writeA(bb ^ 1, abase0, p0);
            writeA(bb ^ 1, abase1, p1);
        }
        __syncthreads();
    }

    // bias (zeros in this problem; kept faithful)
    {
        float bv[10];
        #pragma unroll
        for (int ct = 0; ct < 10; ++ct) bv[ct] = bias[cg*160 + ct*16 + (lane & 15)];
        #pragma unroll
        for (int rf = 0; rf < 4; ++rf)
            #pragma unroll
            for (int ct = 0; ct < 10; ++ct) {
                acc[rf][ct][0] += bv[ct]; acc[rf][ct][1] += bv[ct];
                acc[rf][ct][2] += bv[ct]; acc[rf][ct][3] += bv[ct];
            }
    }

    // ---- Phase A: gumbel-argmax partial + clean exp-sum partial ----
    const int g = cg >> 1;                        // group (2 waves per g)
    const int goff0 = (cg & 1)*160 + (lane & 15); // col within group
    #pragma unroll
    for (int rf = 0; rf < 4; ++rf) {
        #pragma unroll
        for (int r = 0; r < 4; ++r) {
            const int rowA = rg*64 + rf*16 + ((lane >> 4) << 2) + r;
            const float* grow = gum + ((size_t)(n0 + rowA)*2 + g)*VV + goff0;
            float m1 = -1e30f; int bi = 0; float es = 0.f;
            #pragma unroll
            for (int ct = 0; ct < 10; ++ct) {
                float z  = acc[rf][ct][r];
                float zg = z + grow[ct*16];
                if (zg > m1) { m1 = zg; bi = goff0 + ct*16; }
                es += __expf(z);
            }
            #pragma unroll
            for (int off = 1; off < 16; off <<= 1) {
                float om = __shfl_xor(m1, off);
                int   ob = __shfl_xor(bi, off);
                if (om > m1 || (om == m1 && ob < bi)) { m1 = om; bi = ob; }
                es += __shfl_xor(es, off);
            }
            if ((lane & 15) == 0) {
                pmax[cg][rowA] = m1; pidx[cg][rowA] = bi; psum[cg][rowA] = es;
            }
        }
    }
    for (int c = t; c < EE; c += 512) probs_blk[c] = 0.f;
    __syncthreads();

    // ---- Phase B: cross-wave combine (2 partials per row,group) ----
    if (t < 256) {
        const int row = t & 127, gg = t >> 7;
        const float mA = pmax[gg*2][row], mB = pmax[gg*2+1][row];
        const int   iA = pidx[gg*2][row], iB = pidx[gg*2+1][row];
        fidx[row][gg] = (mB > mA || (mB == mA && iB < iA)) ? iB : iA;
        finv[row][gg] = 1.f / (psum[gg*2][row] + psum[gg*2+1][row]);
    }
    __syncthreads();

    // ---- Phase C: probs accumulation ----
    float pacc[10];
    #pragma unroll
    for (int ct = 0; ct < 10; ++ct) pacc[ct] = 0.f;
    #pragma unroll
    for (int rf = 0; rf < 4; ++rf) {
        #pragma unroll
        for (int r = 0; r < 4; ++r) {
            const int rowA = rg*64 + rf*16 + ((lane >> 4) << 2) + r;
            const float inv = finv[rowA][g];
            #pragma unroll
            for (int ct = 0; ct < 10; ++ct)
                pacc[ct] += __expf(acc[rf][ct][r]) * inv;
        }
    }
    #pragma unroll
    for (int off = 16; off < 64; off <<= 1)
        #pragma unroll
        for (int ct = 0; ct < 10; ++ct)
            pacc[ct] += __shfl_xor(pacc[ct], off);
    if (lane < 16) {
        #pragma unroll
        for (int ct = 0; ct < 10; ++ct)
            atomicAdd(&probs_blk[cg*160 + ct*16 + lane], pacc[ct]);
    }
    __syncthreads();

    const int rep = blockIdx.x & 7;
    for (int c = t; c < EE; c += 512)
        atomicAdd(&probs_rep[rep*EE + c], probs_blk[c]);

    // ---- output: codebook gather (row-uniform idx, coalesced) ----
    for (int i = t; i < BM*256; i += 512) {
        const int row = i >> 8, f4 = i & 255;
        const int gg  = f4 >> 7;
        const int idx = fidx[row][gg];
        const float4 v = *(const float4*)&cb[((size_t)gg*VV + idx)*512 + (size_t)(f4 & 127)*4];
        *(float4*)&out[(size_t)(n0 + row)*DD + (size_t)f4*4] = v;
    }
}

// perplexity from 8-replica probs accumulator
__global__ void perp8_kernel(const float* __restrict__ probs_rep,
                             float* __restrict__ outp)
{
    __shared__ float s0[4], s1[4];
    int t = threadIdx.x;   // 256
    float p0 = 0.f, p1 = 0.f;
    for (int c = t; c < EE; c += 256) {
        float a = 0.f;
        #pragma unroll
        for (int rp = 0; rp < 8; ++rp) a += probs_rep[rp*EE + c];
        a *= (1.0f / NROWS);
        float v = a * logf(a + 1e-7f);
        if (c < VV) p0 += v; else p1 += v;
    }
    #pragma unroll
    for (int off = 1; off < 64; off <<= 1) {
        p0 += __shfl_xor(p0, off);
        p1 += __shfl_xor(p1, off);
    }
    if ((t & 63) == 0) { s0[t >> 6] = p0; s1[t >> 6] = p1; }
    __syncthreads();
    if (t == 0) {
        float a0 = s0[0] + s0[1] + s0[2] + s0[3];
        float a1 = s1[0] + s1[1] + s1[2] + s1[3];
        outp[0] = 0.5f * (expf(-a0) + expf(-a1));
    }
}

extern "C" void kernel_launch(void* const* d_in, const int* in_sizes, int n_in,
                              void* d_out, int out_size, void* d_ws, size_t ws_size,
                              hipStream_t stream)
{
    const float* x   = (const float*)d_in[0];
    const float* W   = (const float*)d_in[1];
    const float* b   = (const float*)d_in[2];
    const float* cb  = (const float*)d_in[3];
    const float* gum = (const float*)d_in[4];
    float* out = (float*)d_out;

    // ws layout: [bp 1.31MB][probs_rep 20KB]
    char* wsp = (char*)d_ws;
    unsigned short* bp = (unsigned short*)wsp;
    const size_t bp_b = (size_t)DD*EE*2;
    float* probs_rep = (float*)(wsp + bp_b);
    const size_t pr_b = 8*EE*sizeof(float);

    hipMemsetAsync(probs_rep, 0, pr_b, stream);
    pack_w<<<320, 256, 0, stream>>>(W, bp);
    fused_vq<<<NROWS / BM, 512, 0, stream>>>(x, bp, b, cb, gum, out, probs_rep);
    perp8_kernel<<<1, 256, 0, stream>>>(probs_rep, out + (out_size - 1));
}